// Round 1
// baseline (3062.165 us; speedup 1.0000x reference)
//
#include <hip/hip_runtime.h>

#define NN 50000
#define NE 800000
#define INF 256
#define HID 256
#define NC 64

__global__ __launch_bounds__(256) void degree_kernel(const int* __restrict__ src,
    const int* __restrict__ dst, float* __restrict__ deg_out, float* __restrict__ deg_in, int E)
{
    int e = blockIdx.x * 256 + threadIdx.x;
    if (e < E) {
        atomicAdd(&deg_out[src[e]], 1.0f);
        atomicAdd(&deg_in[dst[e]], 1.0f);
    }
}

__global__ __launch_bounds__(256) void invsqrt_kernel(float* __restrict__ deg, int n)
{
    int i = blockIdx.x * 256 + threadIdx.x;
    if (i < n) deg[i] = rsqrtf(fmaxf(deg[i], 1.0f));
}

__global__ __launch_bounds__(256) void edge_norm_kernel(const int* __restrict__ src,
    const int* __restrict__ dst, const float* __restrict__ inv_out,
    const float* __restrict__ inv_in, float* __restrict__ enorm, int E)
{
    int e = blockIdx.x * 256 + threadIdx.x;
    if (e < E) enorm[e] = inv_out[src[e]] * inv_in[dst[e]];
}

// Tiled fp32 GEMM: C[M,N] = op(A[M,K]) @ B[K,N]; op = relu(x + biasA[k]) if RELU_BIAS.
// BM=64, BN=64, BK=32, 256 threads, 4x4 micro-tile per thread.
template<bool RELU_BIAS>
__global__ __launch_bounds__(256) void gemm_kernel(const float* __restrict__ A,
    const float* __restrict__ B, float* __restrict__ C, int M, int N, int K,
    const float* __restrict__ biasA)
{
    const int BM = 64, BN = 64, BK = 32;
    __shared__ float As[BK][BM + 4];   // transposed; stride 68 floats = 272B (16B-mult, no bank pathology)
    __shared__ float Bs[BK][BN];
    int tid = threadIdx.x;
    int tx = tid & 15, ty = tid >> 4;
    int rowbase = blockIdx.x * BM;
    int colbase = blockIdx.y * BN;
    float acc[4][4] = {};
    for (int kb = 0; kb < K; kb += BK) {
        #pragma unroll
        for (int l = 0; l < 2; ++l) {           // A tile: 64x32 floats, transposed into LDS
            int idx = tid + l * 256;
            int row = idx >> 3;
            int k4 = idx & 7;
            int grow = rowbase + row; if (grow >= M) grow = M - 1;  // clamp; store is guarded
            float4 av = *(const float4*)&A[(size_t)grow * K + kb + k4 * 4];
            float v[4] = {av.x, av.y, av.z, av.w};
            #pragma unroll
            for (int t = 0; t < 4; ++t) {
                float x = v[t];
                if (RELU_BIAS) x = fmaxf(x + biasA[kb + k4 * 4 + t], 0.0f);
                As[k4 * 4 + t][row] = x;
            }
        }
        #pragma unroll
        for (int l = 0; l < 2; ++l) {           // B tile: 32x64 floats
            int idx = tid + l * 256;
            int kk = idx >> 4;
            int c4 = idx & 15;
            float4 bv = *(const float4*)&B[(size_t)(kb + kk) * N + colbase + c4 * 4];
            *(float4*)&Bs[kk][c4 * 4] = bv;
        }
        __syncthreads();
        #pragma unroll
        for (int kk = 0; kk < BK; ++kk) {
            float4 a = *(const float4*)&As[kk][ty * 4];
            float4 b = *(const float4*)&Bs[kk][tx * 4];
            float av4[4] = {a.x, a.y, a.z, a.w};
            float bv4[4] = {b.x, b.y, b.z, b.w};
            #pragma unroll
            for (int i = 0; i < 4; ++i)
                #pragma unroll
                for (int j = 0; j < 4; ++j)
                    acc[i][j] = fmaf(av4[i], bv4[j], acc[i][j]);
        }
        __syncthreads();
    }
    #pragma unroll
    for (int i = 0; i < 4; ++i) {
        int grow = rowbase + ty * 4 + i;
        if (grow < M) {
            float4 o = {acc[i][0], acc[i][1], acc[i][2], acc[i][3]};
            *(float4*)&C[(size_t)grow * N + colbase + tx * 4] = o;
        }
    }
}

// One wave per edge, 256-wide rows: lane handles float4 at lane*4.
__global__ __launch_bounds__(256) void scatter256_kernel(const float* __restrict__ h,
    const float* __restrict__ enorm, const int* __restrict__ src, const int* __restrict__ dst,
    float* __restrict__ out, int E)
{
    int e = (int)((blockIdx.x * 256 + threadIdx.x) >> 6);
    int lane = threadIdx.x & 63;
    if (e >= E) return;
    int s = src[e], d = dst[e];
    float w = enorm[e];
    float4 v = *(const float4*)&h[(size_t)s * 256 + lane * 4];
    float* o = &out[(size_t)d * 256 + lane * 4];
    atomicAdd(o + 0, v.x * w);
    atomicAdd(o + 1, v.y * w);
    atomicAdd(o + 2, v.z * w);
    atomicAdd(o + 3, v.w * w);
}

// One wave per edge, 64-wide rows: lane handles one float.
__global__ __launch_bounds__(256) void scatter64_kernel(const float* __restrict__ h,
    const float* __restrict__ enorm, const int* __restrict__ src, const int* __restrict__ dst,
    float* __restrict__ out, int E)
{
    int e = (int)((blockIdx.x * 256 + threadIdx.x) >> 6);
    int lane = threadIdx.x & 63;
    if (e >= E) return;
    int s = src[e], d = dst[e];
    float w = enorm[e];
    float v = h[(size_t)s * 64 + lane];
    atomicAdd(&out[(size_t)d * 64 + lane], v * w);
}

__global__ __launch_bounds__(256) void init_out_kernel(float* __restrict__ out,
    const float* __restrict__ b2, int n)
{
    int i = blockIdx.x * 256 + threadIdx.x;
    if (i < n) out[i] = b2[i & 63];
}

extern "C" void kernel_launch(void* const* d_in, const int* in_sizes, int n_in,
                              void* d_out, int out_size, void* d_ws, size_t ws_size,
                              hipStream_t stream)
{
    const float* features = (const float*)d_in[0];
    const int*   edge_index = (const int*)d_in[1];
    const float* W1 = (const float*)d_in[2];
    const float* b1 = (const float*)d_in[3];
    const float* W2 = (const float*)d_in[4];
    const float* b2 = (const float*)d_in[5];
    float* out = (float*)d_out;
    const int* src = edge_index;
    const int* dst = edge_index + NE;

    float* wsf  = (float*)d_ws;
    float* deg  = wsf;                              // 2N floats (deg_out | deg_in) -> becomes inv_sqrt
    float* enorm = wsf + 2 * NN;                    // E floats
    float* t1   = enorm + NE;                       // N*256 floats (X@W1), reused later as t2
    float* agg1 = t1 + (size_t)NN * HID;            // N*256 floats
    float* t2   = t1;                               // reuse: t1 dead after scatter256

    hipMemsetAsync(deg, 0, 2 * NN * sizeof(float), stream);
    hipMemsetAsync(agg1, 0, (size_t)NN * HID * sizeof(float), stream);

    degree_kernel<<<(NE + 255) / 256, 256, 0, stream>>>(src, dst, deg, deg + NN, NE);
    invsqrt_kernel<<<(2 * NN + 255) / 256, 256, 0, stream>>>(deg, 2 * NN);
    edge_norm_kernel<<<(NE + 255) / 256, 256, 0, stream>>>(src, dst, deg, deg + NN, enorm, NE);

    // t1 = X @ W1   [50000,256] @ [256,256]
    gemm_kernel<false><<<dim3((NN + 63) / 64, HID / 64), 256, 0, stream>>>(
        features, W1, t1, NN, HID, INF, nullptr);

    // agg1 = scatter(t1 * enorm)
    scatter256_kernel<<<(NE + 3) / 4, 256, 0, stream>>>(t1, enorm, src, dst, agg1, NE);

    // t2 = relu(agg1 + b1) @ W2   [50000,256] @ [256,64]
    gemm_kernel<true><<<dim3((NN + 63) / 64, NC / 64), 256, 0, stream>>>(
        agg1, W2, t2, NN, NC, HID, b1);

    // out = b2, then scatter(t2 * enorm) on top
    init_out_kernel<<<(NN * NC + 255) / 256, 256, 0, stream>>>(out, b2, NN * NC);
    scatter64_kernel<<<(NE + 3) / 4, 256, 0, stream>>>(t2, enorm, src, dst, out, NE);
}

// Round 2
// 555.868 us; speedup vs baseline: 5.5088x; 5.5088x over previous
//
#include <hip/hip_runtime.h>

#define NN 50000
#define NE 800000
#define INF 256
#define HID 256
#define NC 64

// ---------- CSR build ----------

__global__ __launch_bounds__(256) void count_kernel(const int* __restrict__ src,
    const int* __restrict__ dst, int* __restrict__ cnt_out, int* __restrict__ cnt_in, int E)
{
    int e = blockIdx.x * 256 + threadIdx.x;
    if (e < E) {
        atomicAdd(&cnt_out[src[e]], 1);
        atomicAdd(&cnt_in[dst[e]], 1);
    }
}

__global__ __launch_bounds__(256) void inv_kernel(const int* __restrict__ cnt_out,
    const int* __restrict__ cnt_in, float* __restrict__ inv_out, float* __restrict__ inv_in, int n)
{
    int i = blockIdx.x * 256 + threadIdx.x;
    if (i < n) {
        inv_out[i] = rsqrtf(fmaxf((float)cnt_out[i], 1.0f));
        inv_in[i]  = rsqrtf(fmaxf((float)cnt_in[i], 1.0f));
    }
}

// Exclusive prefix sum of cnt[0..n) into rs[0..n). Single block of 1024.
__global__ __launch_bounds__(1024) void scan_kernel(const int* __restrict__ cnt,
    int* __restrict__ rs, int n)
{
    __shared__ int part[1024];
    int tid = threadIdx.x;
    const int CH = (NN + 1023) / 1024;
    int base = tid * CH;
    int s = 0;
    for (int i = 0; i < CH; ++i) {
        int idx = base + i;
        if (idx < n) s += cnt[idx];
    }
    part[tid] = s;
    __syncthreads();
    for (int off = 1; off < 1024; off <<= 1) {
        int v = (tid >= off) ? part[tid - off] : 0;
        __syncthreads();
        part[tid] += v;
        __syncthreads();
    }
    int run = (tid == 0) ? 0 : part[tid - 1];
    for (int i = 0; i < CH; ++i) {
        int idx = base + i;
        if (idx < n) { rs[idx] = run; run += cnt[idx]; }
    }
}

// Bucket-fill. atomicAdd on rs shifts it to inclusive-prefix form:
// after fill, bucket(n) = [n==0 ? 0 : rs[n-1], rs[n]).
__global__ __launch_bounds__(256) void fill_kernel(const int* __restrict__ src,
    const int* __restrict__ dst, int* __restrict__ rs, int* __restrict__ csr_src, int E)
{
    int e = blockIdx.x * 256 + threadIdx.x;
    if (e < E) {
        int slot = atomicAdd(&rs[dst[e]], 1);
        csr_src[slot] = src[e];
    }
}

// ---------- GEMM (fp32 vector ALU) ----------
// C[M,N] = op(A[M,K]) @ B[K,N]; op = relu(x + biasA[k]) if RELU_BIAS.
template<bool RELU_BIAS>
__global__ __launch_bounds__(256) void gemm_kernel(const float* __restrict__ A,
    const float* __restrict__ B, float* __restrict__ C, int M, int N, int K,
    const float* __restrict__ biasA)
{
    const int BM = 64, BN = 64, BK = 32;
    __shared__ float As[BK][BM + 4];
    __shared__ float Bs[BK][BN];
    int tid = threadIdx.x;
    int tx = tid & 15, ty = tid >> 4;
    int rowbase = blockIdx.x * BM;
    int colbase = blockIdx.y * BN;
    float acc[4][4] = {};
    for (int kb = 0; kb < K; kb += BK) {
        #pragma unroll
        for (int l = 0; l < 2; ++l) {
            int idx = tid + l * 256;
            int row = idx >> 3;
            int k4 = idx & 7;
            int grow = rowbase + row; if (grow >= M) grow = M - 1;
            float4 av = *(const float4*)&A[(size_t)grow * K + kb + k4 * 4];
            float v[4] = {av.x, av.y, av.z, av.w};
            #pragma unroll
            for (int t = 0; t < 4; ++t) {
                float x = v[t];
                if (RELU_BIAS) x = fmaxf(x + biasA[kb + k4 * 4 + t], 0.0f);
                As[k4 * 4 + t][row] = x;
            }
        }
        #pragma unroll
        for (int l = 0; l < 2; ++l) {
            int idx = tid + l * 256;
            int kk = idx >> 4;
            int c4 = idx & 15;
            float4 bv = *(const float4*)&B[(size_t)(kb + kk) * N + colbase + c4 * 4];
            *(float4*)&Bs[kk][c4 * 4] = bv;
        }
        __syncthreads();
        #pragma unroll
        for (int kk = 0; kk < BK; ++kk) {
            float4 a = *(const float4*)&As[kk][ty * 4];
            float4 b = *(const float4*)&Bs[kk][tx * 4];
            float av4[4] = {a.x, a.y, a.z, a.w};
            float bv4[4] = {b.x, b.y, b.z, b.w};
            #pragma unroll
            for (int i = 0; i < 4; ++i)
                #pragma unroll
                for (int j = 0; j < 4; ++j)
                    acc[i][j] = fmaf(av4[i], bv4[j], acc[i][j]);
        }
        __syncthreads();
    }
    #pragma unroll
    for (int i = 0; i < 4; ++i) {
        int grow = rowbase + ty * 4 + i;
        if (grow < M) {
            float4 o = {acc[i][0], acc[i][1], acc[i][2], acc[i][3]};
            *(float4*)&C[(size_t)grow * N + colbase + tx * 4] = o;
        }
    }
}

// ---------- CSR gathers (no atomics) ----------

// One wave per dst node; lane owns float4 at lane*4 of the 256-wide row.
__global__ __launch_bounds__(256) void gather256_kernel(const float* __restrict__ h,
    const int* __restrict__ csr_src, const int* __restrict__ rs,
    const float* __restrict__ inv_out, const float* __restrict__ inv_in,
    float* __restrict__ out, int N)
{
    int n = (int)((blockIdx.x * 256 + threadIdx.x) >> 6);
    int lane = threadIdx.x & 63;
    if (n >= N) return;
    int begin = (n == 0) ? 0 : rs[n - 1];
    int end = rs[n];
    float win = inv_in[n];
    float4 acc = {0.f, 0.f, 0.f, 0.f};
    for (int j = begin; j < end; ++j) {
        int s = csr_src[j];
        float w = inv_out[s] * win;
        float4 v = *(const float4*)&h[(size_t)s * 256 + lane * 4];
        acc.x = fmaf(v.x, w, acc.x);
        acc.y = fmaf(v.y, w, acc.y);
        acc.z = fmaf(v.z, w, acc.z);
        acc.w = fmaf(v.w, w, acc.w);
    }
    *(float4*)&out[(size_t)n * 256 + lane * 4] = acc;
}

// One wave per dst node; lane owns one float of the 64-wide row. Adds b2.
__global__ __launch_bounds__(256) void gather64_kernel(const float* __restrict__ h,
    const int* __restrict__ csr_src, const int* __restrict__ rs,
    const float* __restrict__ inv_out, const float* __restrict__ inv_in,
    const float* __restrict__ b2, float* __restrict__ out, int N)
{
    int n = (int)((blockIdx.x * 256 + threadIdx.x) >> 6);
    int lane = threadIdx.x & 63;
    if (n >= N) return;
    int begin = (n == 0) ? 0 : rs[n - 1];
    int end = rs[n];
    float win = inv_in[n];
    float acc = 0.f;
    for (int j = begin; j < end; ++j) {
        int s = csr_src[j];
        float w = inv_out[s] * win;
        acc = fmaf(h[(size_t)s * 64 + lane], w, acc);
    }
    out[(size_t)n * 64 + lane] = acc + b2[lane];
}

extern "C" void kernel_launch(void* const* d_in, const int* in_sizes, int n_in,
                              void* d_out, int out_size, void* d_ws, size_t ws_size,
                              hipStream_t stream)
{
    const float* features = (const float*)d_in[0];
    const int*   edge_index = (const int*)d_in[1];
    const float* W1 = (const float*)d_in[2];
    const float* b1 = (const float*)d_in[3];
    const float* W2 = (const float*)d_in[4];
    const float* b2 = (const float*)d_in[5];
    float* out = (float*)d_out;
    const int* src = edge_index;
    const int* dst = edge_index + NE;

    int*   cnt_out = (int*)d_ws;                    // N
    int*   cnt_in  = cnt_out + NN;                  // N
    float* inv_out = (float*)(cnt_in + NN);         // N
    float* inv_in  = inv_out + NN;                  // N
    int*   rs      = (int*)(inv_in + NN);           // N
    int*   csr_src = rs + NN;                       // E
    float* t1      = (float*)(csr_src + NE);        // N*HID (51.2 MB)
    float* agg1    = t1 + (size_t)NN * HID;         // N*HID (51.2 MB)
    float* t2      = t1;                            // reuse: t1 dead after gather256

    hipMemsetAsync(cnt_out, 0, 2 * NN * sizeof(int), stream);

    count_kernel<<<(NE + 255) / 256, 256, 0, stream>>>(src, dst, cnt_out, cnt_in, NE);
    inv_kernel<<<(NN + 255) / 256, 256, 0, stream>>>(cnt_out, cnt_in, inv_out, inv_in, NN);
    scan_kernel<<<1, 1024, 0, stream>>>(cnt_in, rs, NN);
    fill_kernel<<<(NE + 255) / 256, 256, 0, stream>>>(src, dst, rs, csr_src, NE);

    // t1 = X @ W1   [50000,256] @ [256,256]
    gemm_kernel<false><<<dim3((NN + 63) / 64, HID / 64), 256, 0, stream>>>(
        features, W1, t1, NN, HID, INF, nullptr);

    // agg1[n] = sum_{e: dst=n} t1[src] * w   (CSR gather, no atomics)
    gather256_kernel<<<(NN * 64 + 255) / 256, 256, 0, stream>>>(
        t1, csr_src, rs, inv_out, inv_in, agg1, NN);

    // t2 = relu(agg1 + b1) @ W2   [50000,256] @ [256,64]
    gemm_kernel<true><<<dim3((NN + 63) / 64, NC / 64), 256, 0, stream>>>(
        agg1, W2, t2, NN, NC, HID, b1);

    // out[n] = sum t2[src]*w + b2
    gather64_kernel<<<(NN * 64 + 255) / 256, 256, 0, stream>>>(
        t2, csr_src, rs, inv_out, inv_in, b2, out, NN);
}